// Round 18
// baseline (200.946 us; speedup 1.0000x reference)
//
#include <hip/hip_runtime.h>
#include <hip/hip_bf16.h>

typedef __attribute__((ext_vector_type(8))) short bf16x8;
typedef __attribute__((ext_vector_type(4))) float f32x4;
typedef __attribute__((ext_vector_type(16))) float f32x16;
typedef __attribute__((ext_vector_type(2))) unsigned int u32x2;

__device__ __forceinline__ float fexp2(float x) { return __builtin_amdgcn_exp2f(x); }

__device__ __forceinline__ ushort f2bf(float x) {
    union { float f; unsigned u; } c; c.f = x;
    unsigned r = c.u + 0x7fff + ((c.u >> 16) & 1);
    return (ushort)(r >> 16);
}

__device__ __forceinline__ unsigned cvtpk(float lo, float hi) {
    unsigned r;
    asm("v_cvt_pk_bf16_f32 %0, %1, %2" : "=v"(r) : "v"(lo), "v"(hi));
    return r;
}

__device__ __forceinline__ void gload16(const void* g, void* l) {
    __builtin_amdgcn_global_load_lds((const __attribute__((address_space(1))) void*)g,
                                     (__attribute__((address_space(3))) void*)l, 16, 0, 0);
}

__device__ __forceinline__ void blockbar() {
    asm volatile("" ::: "memory");
    __builtin_amdgcn_s_barrier();
    asm volatile("" ::: "memory");
}

// ---------------- fused f32 -> bf16 convert ----------------
__global__ void cvt_all(const float* __restrict__ X, const float* __restrict__ wa,
                        const float* __restrict__ wb, const float* __restrict__ wc,
                        const float* __restrict__ wd,
                        ushort* __restrict__ oX, ushort* __restrict__ oWcat,
                        ushort* __restrict__ oWo) {
    const int NX4 = 2097152;
    const int NW4 = 262144;
    const int TOT = NX4 + 4 * NW4;
    int i = blockIdx.x * blockDim.x + threadIdx.x;
    int stride = gridDim.x * blockDim.x;
    for (; i < TOT; i += stride) {
        const float* src; ushort4* dst; int local;
        if (i < NX4) { src = X; local = i; dst = (ushort4*)oX; }
        else {
            int j = i - NX4, sel = j >> 18; local = j & (NW4 - 1);
            src = (sel == 0) ? wa : (sel == 1) ? wb : (sel == 2) ? wc : wd;
            dst = (sel < 3) ? (ushort4*)oWcat + sel * NW4 : (ushort4*)oWo;
        }
        float4 v = ((const float4*)src)[local];
        ushort4 o;
        o.x = f2bf(v.x); o.y = f2bf(v.y); o.z = f2bf(v.z); o.w = f2bf(v.w);
        dst[local] = o;
    }
}

// ---------------- BK=32 pipelined bf16 GEMM, 256x128 tile (QKV projection) ----------------
__global__ __launch_bounds__(512, 4)
void gemm_qkv(const ushort* __restrict__ A, const ushort* __restrict__ Bt,
              const float* __restrict__ bias0, const float* __restrict__ bias1,
              const float* __restrict__ bias2,
              ushort* __restrict__ outb, int M, int N, int K) {
    __shared__ ushort lds[24576];
    const int t = threadIdx.x, lane = t & 63, w = t >> 6;
    const int wm = w >> 1, wn = w & 1;
    const int l15 = lane & 15, lg = lane >> 4;

    const int nbx = N >> 7;
    const int nwg = nbx * (M >> 8);
    const int bid = blockIdx.y * nbx + blockIdx.x;
    const int swz = (bid & 7) * (nwg >> 3) + (bid >> 3);
    const int m0 = (swz / nbx) * 256, n0 = (swz % nbx) * 128;

    const int rA0 = t >> 2, pcb = t & 3;
    const int rA1 = rA0 + 128;
    const int gA0 = pcb ^ ((rA0 >> 1) & 3);
    const int gA1 = pcb ^ ((rA1 >> 1) & 3);
    const ushort* srcA0 = A + (size_t)(m0 + rA0) * K + gA0 * 8;
    const ushort* srcA1 = A + (size_t)(m0 + rA1) * K + gA1 * 8;
    const ushort* srcB  = Bt + (size_t)(n0 + rA0) * K + gA0 * 8;

#define STAGE(ST, KT) { \
    gload16(srcA0 + (KT) * 32, &lds[(ST) * 12288 + t * 8]); \
    gload16(srcA1 + (KT) * 32, &lds[(ST) * 12288 + 4096 + t * 8]); \
    gload16(srcB  + (KT) * 32, &lds[(ST) * 12288 + 8192 + t * 8]); }

    f32x4 acc[4][4] = {};
    const int NT = K >> 5;

    STAGE(0, 0); STAGE(1, 1);

    for (int kt = 0; kt < NT; ++kt) {
        if (kt < NT - 1) asm volatile("s_waitcnt vmcnt(3)" ::: "memory");
        else             asm volatile("s_waitcnt vmcnt(0)" ::: "memory");
        blockbar();

        const ushort* stg = &lds[(kt & 1) * 12288];
        bf16x8 af[4], bfr[4];
#pragma unroll
        for (int mi = 0; mi < 4; mi++) {
            int row = wm * 64 + mi * 16 + l15;
            af[mi] = *(const bf16x8*)&stg[row * 32 + ((lg ^ ((row >> 1) & 3)) << 3)];
        }
#pragma unroll
        for (int ni = 0; ni < 4; ni++) {
            int row = wn * 64 + ni * 16 + l15;
            bfr[ni] = *(const bf16x8*)&stg[8192 + row * 32 + ((lg ^ ((row >> 1) & 3)) << 3)];
        }

        __builtin_amdgcn_s_setprio(1);
#pragma unroll
        for (int mi = 0; mi < 4; mi++)
#pragma unroll
            for (int ni = 0; ni < 4; ni++)
                acc[mi][ni] = __builtin_amdgcn_mfma_f32_16x16x32_bf16(af[mi], bfr[ni], acc[mi][ni], 0, 0, 0);
        __builtin_amdgcn_s_setprio(0);

        asm volatile("s_waitcnt lgkmcnt(0)" ::: "memory");
        blockbar();
        if (kt + 2 < NT) STAGE((kt & 1), kt + 2);
    }
#undef STAGE

#pragma unroll
    for (int mi = 0; mi < 4; mi++)
#pragma unroll
        for (int ni = 0; ni < 4; ni++)
#pragma unroll
            for (int r = 0; r < 4; r++) {
                int gm = m0 + wm * 64 + mi * 16 + lg * 4 + r;
                int gn = n0 + wn * 64 + ni * 16 + l15;
                const float* bp = (gn < 1024) ? bias0 : ((gn < 2048) ? bias1 : bias2);
                float v = acc[mi][ni][r] + bp[gn & 1023];
                if (gn < 1024) v *= 0.18033688011f;  // 0.125 * log2(e)
                int proj = gn >> 10, nn = gn & 1023;
                int h = nn >> 6, d = nn & 63;
                int b = gm >> 11, s = gm & 2047;
                outb[(size_t)proj * 8388608 + ((((size_t)b << 4) + h) * 2048 + s) * 64 + d] = f2bf(v);
            }
}

// ---------------- 2-phase pipelined bf16 GEMM (out projection, r15-verified) ----------------
__global__ __launch_bounds__(512, 2)
void gemm_outp(const ushort* __restrict__ A, const ushort* __restrict__ Bt,
               const float* __restrict__ bias0,
               float* __restrict__ outf, int M, int N, int K) {
    __shared__ ushort lds[49152];
    const int t = threadIdx.x, lane = t & 63, w = t >> 6;
    const int wm = w >> 1, wn = w & 1;
    const int l15 = lane & 15, lg = lane >> 4;
    const int sw7 = l15 & 7;

    const int nbx = N >> 7;
    const int nwg = nbx * (M >> 8);
    const int bid = blockIdx.y * nbx + blockIdx.x;
    const int swz = (bid & 7) * (nwg >> 3) + (bid >> 3);
    const int m0 = (swz / nbx) * 256, n0 = (swz % nbx) * 128;

    const int srow = lane >> 3;
    const int gcb = (lane & 7) ^ srow;
    const ushort* gsrc[6];
#pragma unroll
    for (int s = 0; s < 4; s++)
        gsrc[s] = A + (size_t)(m0 + s * 64 + w * 8 + srow) * K + gcb * 8;
#pragma unroll
    for (int s = 0; s < 2; s++)
        gsrc[4 + s] = Bt + (size_t)(n0 + s * 64 + w * 8 + srow) * K + gcb * 8;

#define STAGE(ST, KT) { \
    ushort* dst = &lds[(ST) * 24576 + w * 512]; \
    gload16(gsrc[0] + (KT) * 64, dst); \
    gload16(gsrc[1] + (KT) * 64, dst + 4096); \
    gload16(gsrc[2] + (KT) * 64, dst + 8192); \
    gload16(gsrc[3] + (KT) * 64, dst + 12288); \
    gload16(gsrc[4] + (KT) * 64, dst + 16384); \
    gload16(gsrc[5] + (KT) * 64, dst + 20480); }

    f32x4 acc[4][4] = {};
    const int NT = K >> 6;

    STAGE(0, 0); STAGE(1, 1);

    for (int kt = 0; kt < NT; ++kt) {
        if (kt < NT - 1) asm volatile("s_waitcnt vmcnt(6)" ::: "memory");
        else             asm volatile("s_waitcnt vmcnt(0)" ::: "memory");
        blockbar();

        const ushort* stg = &lds[(kt & 1) * 24576];
        bf16x8 a0[4], b0[4], a1[4], b1[4];
#pragma unroll
        for (int mi = 0; mi < 4; mi++) {
            int row = wm * 64 + mi * 16 + l15;
            a0[mi] = *(const bf16x8*)&stg[row * 64 + ((lg ^ sw7) << 3)];
            a1[mi] = *(const bf16x8*)&stg[row * 64 + (((4 + lg) ^ sw7) << 3)];
        }
#pragma unroll
        for (int ni = 0; ni < 4; ni++) {
            int row = wn * 64 + ni * 16 + l15;
            b0[ni] = *(const bf16x8*)&stg[16384 + row * 64 + ((lg ^ sw7) << 3)];
            b1[ni] = *(const bf16x8*)&stg[16384 + row * 64 + (((4 + lg) ^ sw7) << 3)];
        }

        __builtin_amdgcn_s_setprio(1);
#pragma unroll
        for (int mi = 0; mi < 4; mi++)
#pragma unroll
            for (int ni = 0; ni < 4; ni++)
                acc[mi][ni] = __builtin_amdgcn_mfma_f32_16x16x32_bf16(a0[mi], b0[ni], acc[mi][ni], 0, 0, 0);
        __builtin_amdgcn_s_setprio(0);

        asm volatile("s_waitcnt lgkmcnt(0)" ::: "memory");
        blockbar();
        if (kt + 2 < NT) STAGE((kt & 1), kt + 2);

        __builtin_amdgcn_s_setprio(1);
#pragma unroll
        for (int mi = 0; mi < 4; mi++)
#pragma unroll
            for (int ni = 0; ni < 4; ni++)
                acc[mi][ni] = __builtin_amdgcn_mfma_f32_16x16x32_bf16(a1[mi], b1[ni], acc[mi][ni], 0, 0, 0);
        __builtin_amdgcn_s_setprio(0);
    }
#undef STAGE

#pragma unroll
    for (int mi = 0; mi < 4; mi++)
#pragma unroll
        for (int ni = 0; ni < 4; ni++)
#pragma unroll
            for (int r = 0; r < 4; r++) {
                int gm = m0 + wm * 64 + mi * 16 + lg * 4 + r;
                int gn = n0 + wn * 64 + ni * 16 + l15;
                outf[(size_t)gm * N + gn] = acc[mi][ni][r] + bias0[gn];
            }
}

// ---------------- causal flash attention: V-only LDS, K direct from global (dbuf regs) ----------------
// nt = 2qt+2 is even -> tile-pair loop with statically-named kA/kB buffers.
__global__ __launch_bounds__(256, 3)
void attn_fwd(const ushort* __restrict__ Qb, const ushort* __restrict__ Kb,
              const ushort* __restrict__ Vb, ushort* __restrict__ Ab) {
    constexpr int S = 2048;
    __shared__ ushort lds[8192];   // V dbuf only: 2 x 4096 elems (16KB)

    const int bid = blockIdx.x;
    const int qt = 15 - (bid >> 6);
    const int bh = bid & 63;
    const int b = bh >> 4, h = bh & 15;
    const ushort* Qp = Qb + (size_t)bh * S * 64;
    const ushort* Kp = Kb + (size_t)bh * S * 64;
    const ushort* Vp = Vb + (size_t)bh * S * 64;

    const int t = threadIdx.x, lane = t & 63, w = t >> 6;
    const int l15 = lane & 15, l31 = lane & 31, hi = lane >> 5, g = lane >> 4;

    int voff[2];
#pragma unroll
    for (int it = 0; it < 2; it++) {
        int T = (it * 4 + w) * 64 + lane;
        int kvb = T >> 5, db = (T >> 3) & 3, kvr = (T >> 1) & 3, dh = T & 1;
        voff[it] = (kvb * 4 + kvr) * 64 + db * 16 + dh * 8;
    }
    const unsigned vtbase = (unsigned)(uintptr_t)&lds[0]
                          + (hi << 10) + ((g & 1) << 7) + (l15 << 3);

    auto stageV = [&](int phase, int k0) {
#pragma unroll
        for (int it = 0; it < 2; it++)
            gload16(Vp + (size_t)k0 * 64 + voff[it], &lds[(phase << 12) + (((it << 2) + w) << 9)]);
    };

    auto loadK = [&](bf16x8 (&DL)[4], bf16x8 (&DH)[4], int kk0) {
#pragma unroll
        for (int kc = 0; kc < 4; kc++) {
            DL[kc] = *(const bf16x8*)&Kp[(size_t)(kk0 + l31) * 64 + (kc * 2 + hi) * 8];
            DH[kc] = *(const bf16x8*)&Kp[(size_t)(kk0 + 32 + l31) * 64 + (kc * 2 + hi) * 8];
        }
    };

    const int fb = qt * 128 + w * 32;
    const int nt = 2 * qt + 2;   // always even

    bf16x8 qf[4];
#pragma unroll
    for (int kc = 0; kc < 4; kc++)
        qf[kc] = *(const bf16x8*)&Qp[(size_t)(fb + l31) * 64 + kc * 16 + hi * 8];

    float m = -3e38f, ls = 0.f;
    f32x16 O0 = {}, O1 = {};

    bf16x8 kAl[4], kAh[4], kBl[4], kBh[4];

#define TRR(idx, OFFSTR) asm volatile("ds_read_b64_tr_b16 %0, %1 offset:" OFFSTR : "=v"(vb[idx]) : "v"(vtb))

    auto body = [&](bf16x8 (&KL)[4], bf16x8 (&KH)[4], bf16x8 (&NKL)[4], bf16x8 (&NKH)[4],
                    int phase, int tile) {
        const int k0 = tile * 64;
        asm volatile("s_waitcnt vmcnt(0)" ::: "memory");
        blockbar();
        if (tile + 1 < nt) stageV(phase ^ 1, (tile + 1) * 64);

        if (k0 <= fb + 31) {
            f32x16 s0 = {}, s1 = {};
            __builtin_amdgcn_s_setprio(1);
#pragma unroll
            for (int kc = 0; kc < 4; kc++)
                s0 = __builtin_amdgcn_mfma_f32_32x32x16_bf16(KL[kc], qf[kc], s0, 0, 0, 0);
#pragma unroll
            for (int kc = 0; kc < 4; kc++)
                s1 = __builtin_amdgcn_mfma_f32_32x32x16_bf16(KH[kc], qf[kc], s1, 0, 0, 0);
            __builtin_amdgcn_s_setprio(0);

            if (tile + 1 < nt && (tile + 1) * 64 <= fb + 31)
                loadK(NKL, NKH, (tile + 1) * 64);

            const bool diag = (k0 + 63 > fb);
            if (diag) {
                const int rel = fb + l31 - k0 - 4 * hi;
#pragma unroll
                for (int r = 0; r < 16; r++) {
                    int kvc = (r & 3) + 8 * (r >> 2);
                    if (kvc > rel)      s0[r] = -1e30f;
                    if (kvc + 32 > rel) s1[r] = -1e30f;
                }
            }
            float pv[32];
#pragma unroll
            for (int r = 0; r < 16; r++) { pv[r] = s0[r]; pv[16 + r] = s1[r]; }
            float mx[16];
#pragma unroll
            for (int i = 0; i < 16; i++) mx[i] = fmaxf(pv[i], pv[i + 16]);
#pragma unroll
            for (int sgap = 8; sgap >= 1; sgap >>= 1)
#pragma unroll
                for (int i = 0; i < sgap; i++) mx[i] = fmaxf(mx[i], mx[i + sgap]);
            float pmax = fmaxf(mx[0], __shfl_xor(mx[0], 32));

            if (!__all(pmax <= m + 8.f)) {
                float mnew = fmaxf(m, pmax);
                float a = fexp2(m - mnew);
                ls *= a;
                float ar[16];
#pragma unroll
                for (int r = 0; r < 16; r++)
                    ar[r] = __shfl(a, (r & 3) + 8 * (r >> 2) + 4 * hi, 32);
#pragma unroll
                for (int r = 0; r < 16; r++) { O0[r] *= ar[r]; O1[r] *= ar[r]; }
                m = mnew;
            }
#pragma unroll
            for (int i = 0; i < 32; i++) pv[i] = fexp2(pv[i] - m);
            float sm[16];
#pragma unroll
            for (int i = 0; i < 16; i++) sm[i] = pv[i] + pv[i + 16];
#pragma unroll
            for (int sgap = 8; sgap >= 1; sgap >>= 1)
#pragma unroll
                for (int i = 0; i < sgap; i++) sm[i] += sm[i + sgap];
            ls += sm[0] + __shfl_xor(sm[0], 32);

            union PAu { bf16x8 v; unsigned wd[4]; } PA[4];
#pragma unroll
            for (int ks = 0; ks < 4; ks++)
#pragma unroll
                for (int i = 0; i < 2; i++) {
                    unsigned xw = cvtpk(pv[8 * ks + 2 * i], pv[8 * ks + 2 * i + 1]);
                    unsigned yw = cvtpk(pv[8 * ks + 2 * i + 4], pv[8 * ks + 2 * i + 5]);
                    asm("v_permlane32_swap_b32 %0, %1" : "+v"(xw), "+v"(yw));
                    PA[ks].wd[i] = xw; PA[ks].wd[2 + i] = yw;
                }

            const unsigned vtb = vtbase + (phase << 13);
            union FragU { bf16x8 v; u32x2 hh[2]; };
            {
                u32x2 vb[8];
                TRR(0, "0");    TRR(1, "512");  TRR(2, "2048"); TRR(3, "2560");
                TRR(4, "4096"); TRR(5, "4608"); TRR(6, "6144"); TRR(7, "6656");
                asm volatile("s_waitcnt lgkmcnt(0)" ::: "memory");
                __builtin_amdgcn_sched_barrier(0);
                __builtin_amdgcn_s_setprio(1);
#pragma unroll
                for (int ks = 0; ks < 4; ks++) {
                    FragU f; f.hh[0] = vb[ks * 2]; f.hh[1] = vb[ks * 2 + 1];
                    O0 = __builtin_amdgcn_mfma_f32_32x32x16_bf16(PA[ks].v, f.v, O0, 0, 0, 0);
                }
                __builtin_amdgcn_s_setprio(0);
            }
            {
                u32x2 vb[8];
                TRR(0, "256");  TRR(1, "768");  TRR(2, "2304"); TRR(3, "2816");
                TRR(4, "4352"); TRR(5, "4864"); TRR(6, "6400"); TRR(7, "6912");
                asm volatile("s_waitcnt lgkmcnt(0)" ::: "memory");
                __builtin_amdgcn_sched_barrier(0);
                __builtin_amdgcn_s_setprio(1);
#pragma unroll
                for (int ks = 0; ks < 4; ks++) {
                    FragU f; f.hh[0] = vb[ks * 2]; f.hh[1] = vb[ks * 2 + 1];
                    O1 = __builtin_amdgcn_mfma_f32_32x32x16_bf16(PA[ks].v, f.v, O1, 0, 0, 0);
                }
                __builtin_amdgcn_s_setprio(0);
            }
        }
    };

    loadK(kAl, kAh, 0);
    stageV(0, 0);

    for (int tp = 0; tp < nt; tp += 2) {
        body(kAl, kAh, kBl, kBh, 0, tp);
        body(kBl, kBh, kAl, kAh, 1, tp + 1);
    }
#undef TRR

    float inv[16];
#pragma unroll
    for (int r = 0; r < 16; r++)
        inv[r] = __builtin_amdgcn_rcpf(__shfl(ls, (r & 3) + 8 * (r >> 2) + 4 * hi, 32));
#pragma unroll
    for (int r = 0; r < 16; r++) {
        int q = fb + (r & 3) + 8 * (r >> 2) + 4 * hi;
        size_t base = ((size_t)b * 2048 + q) * 1024 + h * 64;
        Ab[base + l31]      = f2bf(O0[r] * inv[r]);
        Ab[base + 32 + l31] = f2bf(O1[r] * inv[r]);
    }
}

// ---------------- launch ----------------
extern "C" void kernel_launch(void* const* d_in, const int* in_sizes, int n_in,
                              void* d_out, int out_size, void* d_ws, size_t ws_size,
                              hipStream_t stream) {
    const float* query = (const float*)d_in[0];
    const float* Wq = (const float*)d_in[2];
    const float* bq = (const float*)d_in[3];
    const float* Wk = (const float*)d_in[4];
    const float* bk = (const float*)d_in[5];
    const float* Wv = (const float*)d_in[6];
    const float* bv = (const float*)d_in[7];
    const float* Wo = (const float*)d_in[8];
    const float* bo = (const float*)d_in[9];
    float* out = (float*)d_out;

    char* ws = (char*)d_ws;
    const size_t SZ_X = 8192ull * 1024 * 2;
    const size_t SZ_W = 1024ull * 1024 * 2;
    ushort* Xb   = (ushort*)(ws);
    ushort* Wcat = (ushort*)(ws + SZ_X);
    ushort* Wob  = (ushort*)(ws + SZ_X + 3 * SZ_W);
    ushort* QKVb = (ushort*)(ws + SZ_X + 4 * SZ_W);
    ushort* Ab   = (ushort*)(ws + 4 * SZ_X + 4 * SZ_W);

    cvt_all<<<2048, 256, 0, stream>>>(query, Wq, Wk, Wv, Wo, Xb, Wcat, Wob);

    gemm_qkv<<<dim3(3072 / 128, 8192 / 256), 512, 0, stream>>>(
        Xb, Wcat, bq, bk, bv, QKVb, 8192, 3072, 1024);

    attn_fwd<<<1024, 256, 0, stream>>>(QKVb, QKVb + 8388608, QKVb + 2 * 8388608, Ab);

    gemm_outp<<<dim3(1024 / 128, 8192 / 256), 512, 0, stream>>>(
        Ab, Wob, bo, out, 8192, 1024, 1024);
}

// Round 19
// 154.026 us; speedup vs baseline: 1.3046x; 1.3046x over previous
//
#include <hip/hip_runtime.h>
#include <hip/hip_bf16.h>

typedef __attribute__((ext_vector_type(8))) short bf16x8;
typedef __attribute__((ext_vector_type(4))) float f32x4;
typedef __attribute__((ext_vector_type(16))) float f32x16;
typedef __attribute__((ext_vector_type(2))) unsigned int u32x2;

__device__ __forceinline__ float fexp2(float x) { return __builtin_amdgcn_exp2f(x); }

__device__ __forceinline__ ushort f2bf(float x) {
    union { float f; unsigned u; } c; c.f = x;
    unsigned r = c.u + 0x7fff + ((c.u >> 16) & 1);
    return (ushort)(r >> 16);
}

__device__ __forceinline__ unsigned cvtpk(float lo, float hi) {
    unsigned r;
    asm("v_cvt_pk_bf16_f32 %0, %1, %2" : "=v"(r) : "v"(lo), "v"(hi));
    return r;
}

__device__ __forceinline__ void gload16(const void* g, void* l) {
    __builtin_amdgcn_global_load_lds((const __attribute__((address_space(1))) void*)g,
                                     (__attribute__((address_space(3))) void*)l, 16, 0, 0);
}

__device__ __forceinline__ void blockbar() {
    asm volatile("" ::: "memory");
    __builtin_amdgcn_s_barrier();
    asm volatile("" ::: "memory");
}

// ---------------- fused f32 -> bf16 convert ----------------
__global__ void cvt_all(const float* __restrict__ X, const float* __restrict__ wa,
                        const float* __restrict__ wb, const float* __restrict__ wc,
                        const float* __restrict__ wd,
                        ushort* __restrict__ oX, ushort* __restrict__ oWcat,
                        ushort* __restrict__ oWo) {
    const int NX4 = 2097152;
    const int NW4 = 262144;
    const int TOT = NX4 + 4 * NW4;
    int i = blockIdx.x * blockDim.x + threadIdx.x;
    int stride = gridDim.x * blockDim.x;
    for (; i < TOT; i += stride) {
        const float* src; ushort4* dst; int local;
        if (i < NX4) { src = X; local = i; dst = (ushort4*)oX; }
        else {
            int j = i - NX4, sel = j >> 18; local = j & (NW4 - 1);
            src = (sel == 0) ? wa : (sel == 1) ? wb : (sel == 2) ? wc : wd;
            dst = (sel < 3) ? (ushort4*)oWcat + sel * NW4 : (ushort4*)oWo;
        }
        float4 v = ((const float4*)src)[local];
        ushort4 o;
        o.x = f2bf(v.x); o.y = f2bf(v.y); o.z = f2bf(v.z); o.w = f2bf(v.w);
        dst[local] = o;
    }
}

// ---------------- BK=32 pipelined bf16 GEMM, 256x128 tile (QKV projection) ----------------
// 512 thr (8 waves 4Mx2N, 64x64/wave), 2-stage dbuf (48KB), counted vmcnt(3),
// colblk swizzle pcb = cb ^ ((row>>1)&3). Q pre-scaled by 0.125*log2(e).
__global__ __launch_bounds__(512, 4)
void gemm_qkv(const ushort* __restrict__ A, const ushort* __restrict__ Bt,
              const float* __restrict__ bias0, const float* __restrict__ bias1,
              const float* __restrict__ bias2,
              ushort* __restrict__ outb, int M, int N, int K) {
    __shared__ ushort lds[24576];
    const int t = threadIdx.x, lane = t & 63, w = t >> 6;
    const int wm = w >> 1, wn = w & 1;
    const int l15 = lane & 15, lg = lane >> 4;

    const int nbx = N >> 7;
    const int nwg = nbx * (M >> 8);
    const int bid = blockIdx.y * nbx + blockIdx.x;
    const int swz = (bid & 7) * (nwg >> 3) + (bid >> 3);
    const int m0 = (swz / nbx) * 256, n0 = (swz % nbx) * 128;

    const int rA0 = t >> 2, pcb = t & 3;
    const int rA1 = rA0 + 128;
    const int gA0 = pcb ^ ((rA0 >> 1) & 3);
    const int gA1 = pcb ^ ((rA1 >> 1) & 3);
    const ushort* srcA0 = A + (size_t)(m0 + rA0) * K + gA0 * 8;
    const ushort* srcA1 = A + (size_t)(m0 + rA1) * K + gA1 * 8;
    const ushort* srcB  = Bt + (size_t)(n0 + rA0) * K + gA0 * 8;

#define STAGE(ST, KT) { \
    gload16(srcA0 + (KT) * 32, &lds[(ST) * 12288 + t * 8]); \
    gload16(srcA1 + (KT) * 32, &lds[(ST) * 12288 + 4096 + t * 8]); \
    gload16(srcB  + (KT) * 32, &lds[(ST) * 12288 + 8192 + t * 8]); }

    f32x4 acc[4][4] = {};
    const int NT = K >> 5;

    STAGE(0, 0); STAGE(1, 1);

    for (int kt = 0; kt < NT; ++kt) {
        if (kt < NT - 1) asm volatile("s_waitcnt vmcnt(3)" ::: "memory");
        else             asm volatile("s_waitcnt vmcnt(0)" ::: "memory");
        blockbar();

        const ushort* stg = &lds[(kt & 1) * 12288];
        bf16x8 af[4], bfr[4];
#pragma unroll
        for (int mi = 0; mi < 4; mi++) {
            int row = wm * 64 + mi * 16 + l15;
            af[mi] = *(const bf16x8*)&stg[row * 32 + ((lg ^ ((row >> 1) & 3)) << 3)];
        }
#pragma unroll
        for (int ni = 0; ni < 4; ni++) {
            int row = wn * 64 + ni * 16 + l15;
            bfr[ni] = *(const bf16x8*)&stg[8192 + row * 32 + ((lg ^ ((row >> 1) & 3)) << 3)];
        }

        __builtin_amdgcn_s_setprio(1);
#pragma unroll
        for (int mi = 0; mi < 4; mi++)
#pragma unroll
            for (int ni = 0; ni < 4; ni++)
                acc[mi][ni] = __builtin_amdgcn_mfma_f32_16x16x32_bf16(af[mi], bfr[ni], acc[mi][ni], 0, 0, 0);
        __builtin_amdgcn_s_setprio(0);

        asm volatile("s_waitcnt lgkmcnt(0)" ::: "memory");
        blockbar();
        if (kt + 2 < NT) STAGE((kt & 1), kt + 2);
    }
#undef STAGE

#pragma unroll
    for (int mi = 0; mi < 4; mi++)
#pragma unroll
        for (int ni = 0; ni < 4; ni++)
#pragma unroll
            for (int r = 0; r < 4; r++) {
                int gm = m0 + wm * 64 + mi * 16 + lg * 4 + r;
                int gn = n0 + wn * 64 + ni * 16 + l15;
                const float* bp = (gn < 1024) ? bias0 : ((gn < 2048) ? bias1 : bias2);
                float v = acc[mi][ni][r] + bp[gn & 1023];
                if (gn < 1024) v *= 0.18033688011f;  // 0.125 * log2(e)
                int proj = gn >> 10, nn = gn & 1023;
                int h = nn >> 6, d = nn & 63;
                int b = gm >> 11, s = gm & 2047;
                outb[(size_t)proj * 8388608 + ((((size_t)b << 4) + h) * 2048 + s) * 64 + d] = f2bf(v);
            }
}

// ---------------- 2-phase pipelined bf16 GEMM (out projection) ----------------
__global__ __launch_bounds__(512, 2)
void gemm_outp(const ushort* __restrict__ A, const ushort* __restrict__ Bt,
               const float* __restrict__ bias0,
               float* __restrict__ outf, int M, int N, int K) {
    __shared__ ushort lds[49152];
    const int t = threadIdx.x, lane = t & 63, w = t >> 6;
    const int wm = w >> 1, wn = w & 1;
    const int l15 = lane & 15, lg = lane >> 4;
    const int sw7 = l15 & 7;

    const int nbx = N >> 7;
    const int nwg = nbx * (M >> 8);
    const int bid = blockIdx.y * nbx + blockIdx.x;
    const int swz = (bid & 7) * (nwg >> 3) + (bid >> 3);
    const int m0 = (swz / nbx) * 256, n0 = (swz % nbx) * 128;

    const int srow = lane >> 3;
    const int gcb = (lane & 7) ^ srow;
    const ushort* gsrc[6];
#pragma unroll
    for (int s = 0; s < 4; s++)
        gsrc[s] = A + (size_t)(m0 + s * 64 + w * 8 + srow) * K + gcb * 8;
#pragma unroll
    for (int s = 0; s < 2; s++)
        gsrc[4 + s] = Bt + (size_t)(n0 + s * 64 + w * 8 + srow) * K + gcb * 8;

#define STAGE(ST, KT) { \
    ushort* dst = &lds[(ST) * 24576 + w * 512]; \
    gload16(gsrc[0] + (KT) * 64, dst); \
    gload16(gsrc[1] + (KT) * 64, dst + 4096); \
    gload16(gsrc[2] + (KT) * 64, dst + 8192); \
    gload16(gsrc[3] + (KT) * 64, dst + 12288); \
    gload16(gsrc[4] + (KT) * 64, dst + 16384); \
    gload16(gsrc[5] + (KT) * 64, dst + 20480); }

    f32x4 acc[4][4] = {};
    const int NT = K >> 6;

    STAGE(0, 0); STAGE(1, 1);

    for (int kt = 0; kt < NT; ++kt) {
        if (kt < NT - 1) asm volatile("s_waitcnt vmcnt(6)" ::: "memory");
        else             asm volatile("s_waitcnt vmcnt(0)" ::: "memory");
        blockbar();

        const ushort* stg = &lds[(kt & 1) * 24576];
        bf16x8 a0[4], b0[4], a1[4], b1[4];
#pragma unroll
        for (int mi = 0; mi < 4; mi++) {
            int row = wm * 64 + mi * 16 + l15;
            a0[mi] = *(const bf16x8*)&stg[row * 64 + ((lg ^ sw7) << 3)];
            a1[mi] = *(const bf16x8*)&stg[row * 64 + (((4 + lg) ^ sw7) << 3)];
        }
#pragma unroll
        for (int ni = 0; ni < 4; ni++) {
            int row = wn * 64 + ni * 16 + l15;
            b0[ni] = *(const bf16x8*)&stg[16384 + row * 64 + ((lg ^ sw7) << 3)];
            b1[ni] = *(const bf16x8*)&stg[16384 + row * 64 + (((4 + lg) ^ sw7) << 3)];
        }

        __builtin_amdgcn_s_setprio(1);
#pragma unroll
        for (int mi = 0; mi < 4; mi++)
#pragma unroll
            for (int ni = 0; ni < 4; ni++)
                acc[mi][ni] = __builtin_amdgcn_mfma_f32_16x16x32_bf16(a0[mi], b0[ni], acc[mi][ni], 0, 0, 0);
        __builtin_amdgcn_s_setprio(0);

        asm volatile("s_waitcnt lgkmcnt(0)" ::: "memory");
        blockbar();
        if (kt + 2 < NT) STAGE((kt & 1), kt + 2);

        __builtin_amdgcn_s_setprio(1);
#pragma unroll
        for (int mi = 0; mi < 4; mi++)
#pragma unroll
            for (int ni = 0; ni < 4; ni++)
                acc[mi][ni] = __builtin_amdgcn_mfma_f32_16x16x32_bf16(a1[mi], b1[ni], acc[mi][ni], 0, 0, 0);
        __builtin_amdgcn_s_setprio(0);
    }
#undef STAGE

#pragma unroll
    for (int mi = 0; mi < 4; mi++)
#pragma unroll
        for (int ni = 0; ni < 4; ni++)
#pragma unroll
            for (int r = 0; r < 4; r++) {
                int gm = m0 + wm * 64 + mi * 16 + lg * 4 + r;
                int gn = n0 + wn * 64 + ni * 16 + l15;
                outf[(size_t)gm * N + gn] = acc[mi][ni][r] + bias0[gn];
            }
}

// ---------------- causal flash attention (round-15 verified: 1 barrier/tile, K+V LDS) ----------------
__global__ __launch_bounds__(256, 4)
void attn_fwd(const ushort* __restrict__ Qb, const ushort* __restrict__ Kb,
              const ushort* __restrict__ Vb, ushort* __restrict__ Ab) {
    constexpr int S = 2048;
    __shared__ ushort lds[16384];

    const int bid = blockIdx.x;
    const int qt = 15 - (bid >> 6);
    const int bh = bid & 63;
    const int b = bh >> 4, h = bh & 15;
    const ushort* Qp = Qb + (size_t)bh * S * 64;
    const ushort* Kp = Kb + (size_t)bh * S * 64;
    const ushort* Vp = Vb + (size_t)bh * S * 64;

    const int t = threadIdx.x, lane = t & 63, w = t >> 6;
    const int l15 = lane & 15, l31 = lane & 31, hi = lane >> 5, g = lane >> 4;

    int koff[2], voff[2];
#pragma unroll
    for (int i = 0; i < 2; i++) {
        int row = (w * 2 + i) * 8 + (lane >> 3);
        int gg = (lane & 7) ^ ((row ^ (row >> 3)) & 7);
        koff[i] = row * 64 + gg * 8;
    }
#pragma unroll
    for (int it = 0; it < 2; it++) {
        int T = (it * 4 + w) * 64 + lane;
        int kvb = T >> 5, db = (T >> 3) & 3, kvr = (T >> 1) & 3, dh = T & 1;
        voff[it] = (kvb * 4 + kvr) * 64 + db * 16 + dh * 8;
    }
    const unsigned vtbase = (unsigned)(uintptr_t)&lds[8192]
                          + (hi << 10) + ((g & 1) << 7) + (l15 << 3);

    auto stage = [&](int phase, int k0) {
#pragma unroll
        for (int i = 0; i < 2; i++)
            gload16(Kp + (size_t)k0 * 64 + koff[i], &lds[(phase << 12) + ((w * 2 + i) << 9)]);
#pragma unroll
        for (int it = 0; it < 2; it++)
            gload16(Vp + (size_t)k0 * 64 + voff[it], &lds[8192 + (phase << 12) + (((it << 2) + w) << 9)]);
    };

    const int fb = qt * 128 + w * 32;
    const int nt = 2 * qt + 2;

    bf16x8 qf[4];
#pragma unroll
    for (int kc = 0; kc < 4; kc++)
        qf[kc] = *(const bf16x8*)&Qp[(size_t)(fb + l31) * 64 + kc * 16 + hi * 8];

    float m = -3e38f, ls = 0.f;
    f32x16 O0 = {}, O1 = {};

    stage(0, 0);

    for (int tile = 0; tile < nt; tile++) {
        const int phase = tile & 1;
        const int k0 = tile * 64;
        asm volatile("s_waitcnt vmcnt(0)" ::: "memory");
        blockbar();
        if (tile + 1 < nt) stage(phase ^ 1, (tile + 1) * 64);

        if (k0 <= fb + 31) {
            const ushort* Kc = &lds[phase << 12];
            f32x16 s0 = {}, s1 = {};
            {
                bf16x8 kf[4];
#pragma unroll
                for (int kc = 0; kc < 4; kc++) {
                    int row = l31;
                    int sw = (row ^ (row >> 3)) & 7;
                    kf[kc] = *(const bf16x8*)&Kc[row * 64 + (((kc * 2 + hi) ^ sw) << 3)];
                }
                __builtin_amdgcn_s_setprio(1);
#pragma unroll
                for (int kc = 0; kc < 4; kc++)
                    s0 = __builtin_amdgcn_mfma_f32_32x32x16_bf16(kf[kc], qf[kc], s0, 0, 0, 0);
                __builtin_amdgcn_s_setprio(0);
            }
            {
                bf16x8 kf[4];
#pragma unroll
                for (int kc = 0; kc < 4; kc++) {
                    int row = 32 + l31;
                    int sw = (row ^ (row >> 3)) & 7;
                    kf[kc] = *(const bf16x8*)&Kc[row * 64 + (((kc * 2 + hi) ^ sw) << 3)];
                }
                __builtin_amdgcn_s_setprio(1);
#pragma unroll
                for (int kc = 0; kc < 4; kc++)
                    s1 = __builtin_amdgcn_mfma_f32_32x32x16_bf16(kf[kc], qf[kc], s1, 0, 0, 0);
                __builtin_amdgcn_s_setprio(0);
            }

            const bool diag = (k0 + 63 > fb);
            if (diag) {
                const int rel = fb + l31 - k0 - 4 * hi;
#pragma unroll
                for (int r = 0; r < 16; r++) {
                    int kvc = (r & 3) + 8 * (r >> 2);
                    if (kvc > rel)      s0[r] = -1e30f;
                    if (kvc + 32 > rel) s1[r] = -1e30f;
                }
            }
            float pv[32];
#pragma unroll
            for (int r = 0; r < 16; r++) { pv[r] = s0[r]; pv[16 + r] = s1[r]; }
            float mx[16];
#pragma unroll
            for (int i = 0; i < 16; i++) mx[i] = fmaxf(pv[i], pv[i + 16]);
#pragma unroll
            for (int sgap = 8; sgap >= 1; sgap >>= 1)
#pragma unroll
                for (int i = 0; i < sgap; i++) mx[i] = fmaxf(mx[i], mx[i + sgap]);
            float pmax = fmaxf(mx[0], __shfl_xor(mx[0], 32));

            if (!__all(pmax <= m + 8.f)) {
                float mnew = fmaxf(m, pmax);
                float a = fexp2(m - mnew);
                ls *= a;
                float ar[16];
#pragma unroll
                for (int r = 0; r < 16; r++)
                    ar[r] = __shfl(a, (r & 3) + 8 * (r >> 2) + 4 * hi, 32);
#pragma unroll
                for (int r = 0; r < 16; r++) { O0[r] *= ar[r]; O1[r] *= ar[r]; }
                m = mnew;
            }
#pragma unroll
            for (int i = 0; i < 32; i++) pv[i] = fexp2(pv[i] - m);
            float sm[16];
#pragma unroll
            for (int i = 0; i < 16; i++) sm[i] = pv[i] + pv[i + 16];
#pragma unroll
            for (int sgap = 8; sgap >= 1; sgap >>= 1)
#pragma unroll
                for (int i = 0; i < sgap; i++) sm[i] += sm[i + sgap];
            ls += sm[0] + __shfl_xor(sm[0], 32);

            union PAu { bf16x8 v; unsigned wd[4]; } PA[4];
#pragma unroll
            for (int ks = 0; ks < 4; ks++)
#pragma unroll
                for (int i = 0; i < 2; i++) {
                    unsigned xw = cvtpk(pv[8 * ks + 2 * i], pv[8 * ks + 2 * i + 1]);
                    unsigned yw = cvtpk(pv[8 * ks + 2 * i + 4], pv[8 * ks + 2 * i + 5]);
                    asm("v_permlane32_swap_b32 %0, %1" : "+v"(xw), "+v"(yw));
                    PA[ks].wd[i] = xw; PA[ks].wd[2 + i] = yw;
                }

            const unsigned vtb = vtbase + (phase << 13);
            u32x2 vb[16];
#define TRR(idx, OFFSTR) asm volatile("ds_read_b64_tr_b16 %0, %1 offset:" OFFSTR : "=v"(vb[idx]) : "v"(vtb))
            TRR(0, "0");    TRR(1, "512");  TRR(2, "2048"); TRR(3, "2560");
            TRR(4, "4096"); TRR(5, "4608"); TRR(6, "6144"); TRR(7, "6656");
            TRR(8, "256");  TRR(9, "768");  TRR(10, "2304"); TRR(11, "2816");
            TRR(12, "4352"); TRR(13, "4864"); TRR(14, "6400"); TRR(15, "6912");
#undef TRR
            union FragU { bf16x8 v; u32x2 hh[2]; };
            asm volatile("s_waitcnt lgkmcnt(8)" ::: "memory");
            __builtin_amdgcn_sched_barrier(0);
            __builtin_amdgcn_s_setprio(1);
#pragma unroll
            for (int ks = 0; ks < 4; ks++) {
                FragU f; f.hh[0] = vb[ks * 2]; f.hh[1] = vb[ks * 2 + 1];
                O0 = __builtin_amdgcn_mfma_f32_32x32x16_bf16(PA[ks].v, f.v, O0, 0, 0, 0);
            }
            __builtin_amdgcn_s_setprio(0);
            asm volatile("s_waitcnt lgkmcnt(0)" ::: "memory");
            __builtin_amdgcn_sched_barrier(0);
            __builtin_amdgcn_s_setprio(1);
#pragma unroll
            for (int ks = 0; ks < 4; ks++) {
                FragU f; f.hh[0] = vb[8 + ks * 2]; f.hh[1] = vb[8 + ks * 2 + 1];
                O1 = __builtin_amdgcn_mfma_f32_32x32x16_bf16(PA[ks].v, f.v, O1, 0, 0, 0);
            }
            __builtin_amdgcn_s_setprio(0);
        }
    }

    float inv[16];
#pragma unroll
    for (int r = 0; r < 16; r++)
        inv[r] = __builtin_amdgcn_rcpf(__shfl(ls, (r & 3) + 8 * (r >> 2) + 4 * hi, 32));
#pragma unroll
    for (int r = 0; r < 16; r++) {
        int q = fb + (r & 3) + 8 * (r >> 2) + 4 * hi;
        size_t base = ((size_t)b * 2048 + q) * 1024 + h * 64;
        Ab[base + l31]      = f2bf(O0[r] * inv[r]);
        Ab[base + 32 + l31] = f2bf(O1[r] * inv[r]);
    }
}

// ---------------- launch ----------------
extern "C" void kernel_launch(void* const* d_in, const int* in_sizes, int n_in,
                              void* d_out, int out_size, void* d_ws, size_t ws_size,
                              hipStream_t stream) {
    const float* query = (const float*)d_in[0];
    const float* Wq = (const float*)d_in[2];
    const float* bq = (const float*)d_in[3];
    const float* Wk = (const float*)d_in[4];
    const float* bk = (const float*)d_in[5];
    const float* Wv = (const float*)d_in[6];
    const float* bv = (const float*)d_in[7];
    const float* Wo = (const float*)d_in[8];
    const float* bo = (const float*)d_in[9];
    float* out = (float*)d_out;

    char* ws = (char*)d_ws;
    const size_t SZ_X = 8192ull * 1024 * 2;
    const size_t SZ_W = 1024ull * 1024 * 2;
    ushort* Xb   = (ushort*)(ws);
    ushort* Wcat = (ushort*)(ws + SZ_X);
    ushort* Wob  = (ushort*)(ws + SZ_X + 3 * SZ_W);
    ushort* QKVb = (ushort*)(ws + SZ_X + 4 * SZ_W);
    ushort* Ab   = (ushort*)(ws + 4 * SZ_X + 4 * SZ_W);

    cvt_all<<<2048, 256, 0, stream>>>(query, Wq, Wk, Wv, Wo, Xb, Wcat, Wob);

    gemm_qkv<<<dim3(3072 / 128, 8192 / 256), 512, 0, stream>>>(
        Xb, Wcat, bq, bk, bv, QKVb, 8192, 3072, 1024);

    attn_fwd<<<1024, 256, 0, stream>>>(QKVb, QKVb + 8388608, QKVb + 2 * 8388608, Ab);

    gemm_outp<<<dim3(1024 / 128, 8192 / 256), 512, 0, stream>>>(
        Ab, Wob, bo, out, 8192, 1024, 1024);
}

// Round 20
// 152.393 us; speedup vs baseline: 1.3186x; 1.0107x over previous
//
#include <hip/hip_runtime.h>
#include <hip/hip_bf16.h>

typedef __attribute__((ext_vector_type(8))) short bf16x8;
typedef __attribute__((ext_vector_type(4))) float f32x4;
typedef __attribute__((ext_vector_type(16))) float f32x16;
typedef __attribute__((ext_vector_type(2))) unsigned int u32x2;

__device__ __forceinline__ float fexp2(float x) { return __builtin_amdgcn_exp2f(x); }

__device__ __forceinline__ ushort f2bf(float x) {
    union { float f; unsigned u; } c; c.f = x;
    unsigned r = c.u + 0x7fff + ((c.u >> 16) & 1);
    return (ushort)(r >> 16);
}

__device__ __forceinline__ unsigned cvtpk(float lo, float hi) {
    unsigned r;
    asm("v_cvt_pk_bf16_f32 %0, %1, %2" : "=v"(r) : "v"(lo), "v"(hi));
    return r;
}

__device__ __forceinline__ void gload16(const void* g, void* l) {
    __builtin_amdgcn_global_load_lds((const __attribute__((address_space(1))) void*)g,
                                     (__attribute__((address_space(3))) void*)l, 16, 0, 0);
}

__device__ __forceinline__ void blockbar() {
    asm volatile("" ::: "memory");
    __builtin_amdgcn_s_barrier();
    asm volatile("" ::: "memory");
}

// ---------------- fused f32 -> bf16 convert ----------------
__global__ void cvt_all(const float* __restrict__ X, const float* __restrict__ wa,
                        const float* __restrict__ wb, const float* __restrict__ wc,
                        const float* __restrict__ wd,
                        ushort* __restrict__ oX, ushort* __restrict__ oWcat,
                        ushort* __restrict__ oWo) {
    const int NX4 = 2097152;
    const int NW4 = 262144;
    const int TOT = NX4 + 4 * NW4;
    int i = blockIdx.x * blockDim.x + threadIdx.x;
    int stride = gridDim.x * blockDim.x;
    for (; i < TOT; i += stride) {
        const float* src; ushort4* dst; int local;
        if (i < NX4) { src = X; local = i; dst = (ushort4*)oX; }
        else {
            int j = i - NX4, sel = j >> 18; local = j & (NW4 - 1);
            src = (sel == 0) ? wa : (sel == 1) ? wb : (sel == 2) ? wc : wd;
            dst = (sel < 3) ? (ushort4*)oWcat + sel * NW4 : (ushort4*)oWo;
        }
        float4 v = ((const float4*)src)[local];
        ushort4 o;
        o.x = f2bf(v.x); o.y = f2bf(v.y); o.z = f2bf(v.z); o.w = f2bf(v.w);
        dst[local] = o;
    }
}

// ---------------- BK=32, 3-stage ring, 1-barrier/K-tile bf16 GEMM (QKV projection) ----------------
// 256x128 tile, 512 thr (8 waves 4Mx2N, 64x64/wave), 3-stage LDS ring (72KB),
// counted vmcnt(3). Iteration kt: {vmcnt;bar; ds_read buf kt%3; stage kt+2 ->
// buf (kt+2)%3; MFMA}. Hazards proven barrier-transitive (see round-20 notes).
// Q pre-scaled by 0.125*log2(e).
__global__ __launch_bounds__(512, 4)
void gemm_qkv(const ushort* __restrict__ A, const ushort* __restrict__ Bt,
              const float* __restrict__ bias0, const float* __restrict__ bias1,
              const float* __restrict__ bias2,
              ushort* __restrict__ outb, int M, int N, int K) {
    __shared__ ushort lds[36864];   // 3 x 12288 ushorts = 72 KB
    const int t = threadIdx.x, lane = t & 63, w = t >> 6;
    const int wm = w >> 1, wn = w & 1;
    const int l15 = lane & 15, lg = lane >> 4;

    const int nbx = N >> 7;
    const int nwg = nbx * (M >> 8);
    const int bid = blockIdx.y * nbx + blockIdx.x;
    const int swz = (bid & 7) * (nwg >> 3) + (bid >> 3);
    const int m0 = (swz / nbx) * 256, n0 = (swz % nbx) * 128;

    const int rA0 = t >> 2, pcb = t & 3;
    const int rA1 = rA0 + 128;
    const int gA0 = pcb ^ ((rA0 >> 1) & 3);
    const int gA1 = pcb ^ ((rA1 >> 1) & 3);
    const ushort* srcA0 = A + (size_t)(m0 + rA0) * K + gA0 * 8;
    const ushort* srcA1 = A + (size_t)(m0 + rA1) * K + gA1 * 8;
    const ushort* srcB  = Bt + (size_t)(n0 + rA0) * K + gA0 * 8;

#define STAGE(ST, KT) { \
    gload16(srcA0 + (KT) * 32, &lds[(ST) * 12288 + t * 8]); \
    gload16(srcA1 + (KT) * 32, &lds[(ST) * 12288 + 4096 + t * 8]); \
    gload16(srcB  + (KT) * 32, &lds[(ST) * 12288 + 8192 + t * 8]); }

    f32x4 acc[4][4] = {};
    const int NT = K >> 5;

    STAGE(0, 0); STAGE(1, 1);

    for (int kt = 0; kt < NT; ++kt) {
        if (kt < NT - 1) asm volatile("s_waitcnt vmcnt(3)" ::: "memory");
        else             asm volatile("s_waitcnt vmcnt(0)" ::: "memory");
        blockbar();

        const ushort* stg = &lds[(kt % 3) * 12288];
        bf16x8 af[4], bfr[4];
#pragma unroll
        for (int mi = 0; mi < 4; mi++) {
            int row = wm * 64 + mi * 16 + l15;
            af[mi] = *(const bf16x8*)&stg[row * 32 + ((lg ^ ((row >> 1) & 3)) << 3)];
        }
#pragma unroll
        for (int ni = 0; ni < 4; ni++) {
            int row = wn * 64 + ni * 16 + l15;
            bfr[ni] = *(const bf16x8*)&stg[8192 + row * 32 + ((lg ^ ((row >> 1) & 3)) << 3)];
        }

        if (kt + 2 < NT) STAGE((kt + 2) % 3, kt + 2);

        __builtin_amdgcn_s_setprio(1);
#pragma unroll
        for (int mi = 0; mi < 4; mi++)
#pragma unroll
            for (int ni = 0; ni < 4; ni++)
                acc[mi][ni] = __builtin_amdgcn_mfma_f32_16x16x32_bf16(af[mi], bfr[ni], acc[mi][ni], 0, 0, 0);
        __builtin_amdgcn_s_setprio(0);
    }
#undef STAGE

#pragma unroll
    for (int mi = 0; mi < 4; mi++)
#pragma unroll
        for (int ni = 0; ni < 4; ni++)
#pragma unroll
            for (int r = 0; r < 4; r++) {
                int gm = m0 + wm * 64 + mi * 16 + lg * 4 + r;
                int gn = n0 + wn * 64 + ni * 16 + l15;
                const float* bp = (gn < 1024) ? bias0 : ((gn < 2048) ? bias1 : bias2);
                float v = acc[mi][ni][r] + bp[gn & 1023];
                if (gn < 1024) v *= 0.18033688011f;  // 0.125 * log2(e)
                int proj = gn >> 10, nn = gn & 1023;
                int h = nn >> 6, d = nn & 63;
                int b = gm >> 11, s = gm & 2047;
                outb[(size_t)proj * 8388608 + ((((size_t)b << 4) + h) * 2048 + s) * 64 + d] = f2bf(v);
            }
}

// ---------------- 2-phase pipelined bf16 GEMM (out projection) ----------------
__global__ __launch_bounds__(512, 2)
void gemm_outp(const ushort* __restrict__ A, const ushort* __restrict__ Bt,
               const float* __restrict__ bias0,
               float* __restrict__ outf, int M, int N, int K) {
    __shared__ ushort lds[49152];
    const int t = threadIdx.x, lane = t & 63, w = t >> 6;
    const int wm = w >> 1, wn = w & 1;
    const int l15 = lane & 15, lg = lane >> 4;
    const int sw7 = l15 & 7;

    const int nbx = N >> 7;
    const int nwg = nbx * (M >> 8);
    const int bid = blockIdx.y * nbx + blockIdx.x;
    const int swz = (bid & 7) * (nwg >> 3) + (bid >> 3);
    const int m0 = (swz / nbx) * 256, n0 = (swz % nbx) * 128;

    const int srow = lane >> 3;
    const int gcb = (lane & 7) ^ srow;
    const ushort* gsrc[6];
#pragma unroll
    for (int s = 0; s < 4; s++)
        gsrc[s] = A + (size_t)(m0 + s * 64 + w * 8 + srow) * K + gcb * 8;
#pragma unroll
    for (int s = 0; s < 2; s++)
        gsrc[4 + s] = Bt + (size_t)(n0 + s * 64 + w * 8 + srow) * K + gcb * 8;

#define STAGE(ST, KT) { \
    ushort* dst = &lds[(ST) * 24576 + w * 512]; \
    gload16(gsrc[0] + (KT) * 64, dst); \
    gload16(gsrc[1] + (KT) * 64, dst + 4096); \
    gload16(gsrc[2] + (KT) * 64, dst + 8192); \
    gload16(gsrc[3] + (KT) * 64, dst + 12288); \
    gload16(gsrc[4] + (KT) * 64, dst + 16384); \
    gload16(gsrc[5] + (KT) * 64, dst + 20480); }

    f32x4 acc[4][4] = {};
    const int NT = K >> 6;

    STAGE(0, 0); STAGE(1, 1);

    for (int kt = 0; kt < NT; ++kt) {
        if (kt < NT - 1) asm volatile("s_waitcnt vmcnt(6)" ::: "memory");
        else             asm volatile("s_waitcnt vmcnt(0)" ::: "memory");
        blockbar();

        const ushort* stg = &lds[(kt & 1) * 24576];
        bf16x8 a0[4], b0[4], a1[4], b1[4];
#pragma unroll
        for (int mi = 0; mi < 4; mi++) {
            int row = wm * 64 + mi * 16 + l15;
            a0[mi] = *(const bf16x8*)&stg[row * 64 + ((lg ^ sw7) << 3)];
            a1[mi] = *(const bf16x8*)&stg[row * 64 + (((4 + lg) ^ sw7) << 3)];
        }
#pragma unroll
        for (int ni = 0; ni < 4; ni++) {
            int row = wn * 64 + ni * 16 + l15;
            b0[ni] = *(const bf16x8*)&stg[16384 + row * 64 + ((lg ^ sw7) << 3)];
            b1[ni] = *(const bf16x8*)&stg[16384 + row * 64 + (((4 + lg) ^ sw7) << 3)];
        }

        __builtin_amdgcn_s_setprio(1);
#pragma unroll
        for (int mi = 0; mi < 4; mi++)
#pragma unroll
            for (int ni = 0; ni < 4; ni++)
                acc[mi][ni] = __builtin_amdgcn_mfma_f32_16x16x32_bf16(a0[mi], b0[ni], acc[mi][ni], 0, 0, 0);
        __builtin_amdgcn_s_setprio(0);

        asm volatile("s_waitcnt lgkmcnt(0)" ::: "memory");
        blockbar();
        if (kt + 2 < NT) STAGE((kt & 1), kt + 2);

        __builtin_amdgcn_s_setprio(1);
#pragma unroll
        for (int mi = 0; mi < 4; mi++)
#pragma unroll
            for (int ni = 0; ni < 4; ni++)
                acc[mi][ni] = __builtin_amdgcn_mfma_f32_16x16x32_bf16(a1[mi], b1[ni], acc[mi][ni], 0, 0, 0);
        __builtin_amdgcn_s_setprio(0);
    }
#undef STAGE

#pragma unroll
    for (int mi = 0; mi < 4; mi++)
#pragma unroll
        for (int ni = 0; ni < 4; ni++)
#pragma unroll
            for (int r = 0; r < 4; r++) {
                int gm = m0 + wm * 64 + mi * 16 + lg * 4 + r;
                int gn = n0 + wn * 64 + ni * 16 + l15;
                outf[(size_t)gm * N + gn] = acc[mi][ni][r] + bias0[gn];
            }
}

// ---------------- causal flash attention (round-15/19 verified) ----------------
__global__ __launch_bounds__(256, 4)
void attn_fwd(const ushort* __restrict__ Qb, const ushort* __restrict__ Kb,
              const ushort* __restrict__ Vb, ushort* __restrict__ Ab) {
    constexpr int S = 2048;
    __shared__ ushort lds[16384];

    const int bid = blockIdx.x;
    const int qt = 15 - (bid >> 6);
    const int bh = bid & 63;
    const int b = bh >> 4, h = bh & 15;
    const ushort* Qp = Qb + (size_t)bh * S * 64;
    const ushort* Kp = Kb + (size_t)bh * S * 64;
    const ushort* Vp = Vb + (size_t)bh * S * 64;

    const int t = threadIdx.x, lane = t & 63, w = t >> 6;
    const int l15 = lane & 15, l31 = lane & 31, hi = lane >> 5, g = lane >> 4;

    int koff[2], voff[2];
#pragma unroll
    for (int i = 0; i < 2; i++) {
        int row = (w * 2 + i) * 8 + (lane >> 3);
        int gg = (lane & 7) ^ ((row ^ (row >> 3)) & 7);
        koff[i] = row * 64 + gg * 8;
    }
#pragma unroll
    for (int it = 0; it < 2; it++) {
        int T = (it * 4 + w) * 64 + lane;
        int kvb = T >> 5, db = (T >> 3) & 3, kvr = (T >> 1) & 3, dh = T & 1;
        voff[it] = (kvb * 4 + kvr) * 64 + db * 16 + dh * 8;
    }
    const unsigned vtbase = (unsigned)(uintptr_t)&lds[8192]
                          + (hi << 10) + ((g & 1) << 7) + (l15 << 3);

    auto stage = [&](int phase, int k0) {
#pragma unroll
        for (int i = 0; i < 2; i++)
            gload16(Kp + (size_t)k0 * 64 + koff[i], &lds[(phase << 12) + ((w * 2 + i) << 9)]);
#pragma unroll
        for (int it = 0; it < 2; it++)
            gload16(Vp + (size_t)k0 * 64 + voff[it], &lds[8192 + (phase << 12) + (((it << 2) + w) << 9)]);
    };

    const int fb = qt * 128 + w * 32;
    const int nt = 2 * qt + 2;

    bf16x8 qf[4];
#pragma unroll
    for (int kc = 0; kc < 4; kc++)
        qf[kc] = *(const bf16x8*)&Qp[(size_t)(fb + l31) * 64 + kc * 16 + hi * 8];

    float m = -3e38f, ls = 0.f;
    f32x16 O0 = {}, O1 = {};

    stage(0, 0);

    for (int tile = 0; tile < nt; tile++) {
        const int phase = tile & 1;
        const int k0 = tile * 64;
        asm volatile("s_waitcnt vmcnt(0)" ::: "memory");
        blockbar();
        if (tile + 1 < nt) stage(phase ^ 1, (tile + 1) * 64);

        if (k0 <= fb + 31) {
            const ushort* Kc = &lds[phase << 12];
            f32x16 s0 = {}, s1 = {};
            {
                bf16x8 kf[4];
#pragma unroll
                for (int kc = 0; kc < 4; kc++) {
                    int row = l31;
                    int sw = (row ^ (row >> 3)) & 7;
                    kf[kc] = *(const bf16x8*)&Kc[row * 64 + (((kc * 2 + hi) ^ sw) << 3)];
                }
                __builtin_amdgcn_s_setprio(1);
#pragma unroll
                for (int kc = 0; kc < 4; kc++)
                    s0 = __builtin_amdgcn_mfma_f32_32x32x16_bf16(kf[kc], qf[kc], s0, 0, 0, 0);
                __builtin_amdgcn_s_setprio(0);
            }
            {
                bf16x8 kf[4];
#pragma unroll
                for (int kc = 0; kc < 4; kc++) {
                    int row = 32 + l31;
                    int sw = (row ^ (row >> 3)) & 7;
                    kf[kc] = *(const bf16x8*)&Kc[row * 64 + (((kc * 2 + hi) ^ sw) << 3)];
                }
                __builtin_amdgcn_s_setprio(1);
#pragma unroll
                for (int kc = 0; kc < 4; kc++)
                    s1 = __builtin_amdgcn_mfma_f32_32x32x16_bf16(kf[kc], qf[kc], s1, 0, 0, 0);
                __builtin_amdgcn_s_setprio(0);
            }

            const bool diag = (k0 + 63 > fb);
            if (diag) {
                const int rel = fb + l31 - k0 - 4 * hi;
#pragma unroll
                for (int r = 0; r < 16; r++) {
                    int kvc = (r & 3) + 8 * (r >> 2);
                    if (kvc > rel)      s0[r] = -1e30f;
                    if (kvc + 32 > rel) s1[r] = -1e30f;
                }
            }
            float pv[32];
#pragma unroll
            for (int r = 0; r < 16; r++) { pv[r] = s0[r]; pv[16 + r] = s1[r]; }
            float mx[16];
#pragma unroll
            for (int i = 0; i < 16; i++) mx[i] = fmaxf(pv[i], pv[i + 16]);
#pragma unroll
            for (int sgap = 8; sgap >= 1; sgap >>= 1)
#pragma unroll
                for (int i = 0; i < sgap; i++) mx[i] = fmaxf(mx[i], mx[i + sgap]);
            float pmax = fmaxf(mx[0], __shfl_xor(mx[0], 32));

            if (!__all(pmax <= m + 8.f)) {
                float mnew = fmaxf(m, pmax);
                float a = fexp2(m - mnew);
                ls *= a;
                float ar[16];
#pragma unroll
                for (int r = 0; r < 16; r++)
                    ar[r] = __shfl(a, (r & 3) + 8 * (r >> 2) + 4 * hi, 32);
#pragma unroll
                for (int r = 0; r < 16; r++) { O0[r] *= ar[r]; O1[r] *= ar[r]; }
                m = mnew;
            }
#pragma unroll
            for (int i = 0; i < 32; i++) pv[i] = fexp2(pv[i] - m);
            float sm[16];
#pragma unroll
            for (int i = 0; i < 16; i++) sm[i] = pv[i] + pv[i + 16];
#pragma unroll
            for (int sgap = 8; sgap >= 1; sgap >>= 1)
#pragma unroll
                for (int i = 0; i < sgap; i++) sm[i] += sm[i + sgap];
            ls += sm[0] + __shfl_xor(sm[0], 32);

            union PAu { bf16x8 v; unsigned wd[4]; } PA[4];
#pragma unroll
            for (int ks = 0; ks < 4; ks++)
#pragma unroll
                for (int i = 0; i < 2; i++) {
                    unsigned xw = cvtpk(pv[8 * ks + 2 * i], pv[8 * ks + 2 * i + 1]);
                    unsigned yw = cvtpk(pv[8 * ks + 2 * i + 4], pv[8 * ks + 2 * i + 5]);
                    asm("v_permlane32_swap_b32 %0, %1" : "+v"(xw), "+v"(yw));
                    PA[ks].wd[i] = xw; PA[ks].wd[2 + i] = yw;
                }

            const unsigned vtb = vtbase + (phase << 13);
            u32x2 vb[16];
#define TRR(idx, OFFSTR) asm volatile("ds_read_b64_tr_b16 %0, %1 offset:" OFFSTR : "=v"(vb[idx]) : "v"(vtb))
            TRR(0, "0");    TRR(1, "512");  TRR(2, "2048"); TRR(3, "2560");
            TRR(4, "4096"); TRR(5, "4608"); TRR(6, "6144"); TRR(7, "6656");
            TRR(8, "256");  TRR(9, "768");  TRR(10, "2304"); TRR(11, "2816");
            TRR(12, "4352"); TRR(13, "4864"); TRR(14, "6400"); TRR(15, "6912");
#undef TRR
            union FragU { bf16x8 v; u32x2 hh[2]; };
            asm volatile("s_waitcnt lgkmcnt(8)" ::: "memory");
            __builtin_amdgcn_sched_barrier(0);
            __builtin_amdgcn_s_setprio(1);
#pragma unroll
            for (int ks = 0; ks < 4; ks++) {
                FragU f; f.hh[0] = vb[ks * 2]; f.hh[1] = vb[ks * 2 + 1];
                O0 = __builtin_amdgcn_mfma_f32_32x32x16_bf16(PA[ks].v, f.v, O0, 0, 0, 0);
            }
            __builtin_amdgcn_s_setprio(0);
            asm volatile("s_waitcnt lgkmcnt(0)" ::: "memory");
            __builtin_amdgcn_sched_barrier(0);
            __builtin_amdgcn_s_setprio(1);
#pragma unroll
            for (int ks = 0; ks < 4; ks++) {
                FragU f; f.hh[0] = vb[8 + ks * 2]; f.hh[1] = vb[8 + ks * 2 + 1];
                O1 = __builtin_amdgcn_mfma_f32_32x32x16_bf16(PA[ks].v, f.v, O1, 0, 0, 0);
            }
            __builtin_amdgcn_s_setprio(0);
        }
    }

    float inv[16];
#pragma unroll
    for (int r = 0; r < 16; r++)
        inv[r] = __builtin_amdgcn_rcpf(__shfl(ls, (r & 3) + 8 * (r >> 2) + 4 * hi, 32));
#pragma unroll
    for (int r = 0; r < 16; r++) {
        int q = fb + (r & 3) + 8 * (r >> 2) + 4 * hi;
        size_t base = ((size_t)b * 2048 + q) * 1024 + h * 64;
        Ab[base + l31]      = f2bf(O0[r] * inv[r]);
        Ab[base + 32 + l31] = f2bf(O1[r] * inv[r]);
    }
}

// ---------------- launch ----------------
extern "C" void kernel_launch(void* const* d_in, const int* in_sizes, int n_in,
                              void* d_out, int out_size, void* d_ws, size_t ws_size,
                              hipStream_t stream) {
    const float* query = (const float*)d_in[0];
    const float* Wq = (const float*)d_in[2];
    const float* bq = (const float*)d_in[3];
    const float* Wk = (const float*)d_in[4];
    const float* bk = (const float*)d_in[5];
    const float* Wv = (const float*)d_in[6];
    const float* bv = (const float*)d_in[7];
    const float* Wo = (const float*)d_in[8];
    const float* bo = (const float*)d_in[9];
    float* out = (float*)d_out;

    char* ws = (char*)d_ws;
    const size_t SZ_X = 8192ull * 1024 * 2;
    const size_t SZ_W = 1024ull * 1024 * 2;
    ushort* Xb   = (ushort*)(ws);
    ushort* Wcat = (ushort*)(ws + SZ_X);
    ushort* Wob  = (ushort*)(ws + SZ_X + 3 * SZ_W);
    ushort* QKVb = (ushort*)(ws + SZ_X + 4 * SZ_W);
    ushort* Ab   = (ushort*)(ws + 4 * SZ_X + 4 * SZ_W);

    cvt_all<<<2048, 256, 0, stream>>>(query, Wq, Wk, Wv, Wo, Xb, Wcat, Wob);

    gemm_qkv<<<dim3(3072 / 128, 8192 / 256), 512, 0, stream>>>(
        Xb, Wcat, bq, bk, bv, QKVb, 8192, 3072, 1024);

    attn_fwd<<<1024, 256, 0, stream>>>(QKVb, QKVb + 8388608, QKVb + 2 * 8388608, Ab);

    gemm_outp<<<dim3(1024 / 128, 8192 / 256), 512, 0, stream>>>(
        Ab, Wob, bo, out, 8192, 1024, 1024);
}